// Round 3
// baseline (1419.951 us; speedup 1.0000x reference)
//
#include <hip/hip_runtime.h>

#define DIM 128
#define BROWS 64                // rows per bucket (row >> 6)
#define BCAP 1536               // edata capacity per bucket (mean 1024, +16 sigma)
#define BK_EDGES 2048           // edges per k_bucket block (782 blocks -> full CU spread)

typedef __attribute__((ext_vector_type(8))) short short8;   // 8 x bf16 (4 VGPR)
typedef __attribute__((ext_vector_type(4))) float f32x4;    // 4 x f32  (4 VGPR)

__device__ __forceinline__ unsigned short f2bf(float f) {   // RNE fp32->bf16
    unsigned u = __float_as_uint(f);
    u += 0x7fffu + ((u >> 16) & 1u);
    return (unsigned short)(u >> 16);
}
__device__ __forceinline__ float bf2f(unsigned short b) {
    return __uint_as_float(((unsigned)b) << 16);
}

// ---- merged pre-pass: input fp32->bf16 (SPLIT-PAIR layout), weights, zero gcur ----
// inputb word l of a row packs dims (l, l+64): lo ushort = x[l], hi ushort = x[l+64].
// This makes k_gather's per-edge ds_add_f32 addresses stride-1 (2-way bank alias = free).
__global__ void k_pre(const float2* __restrict__ in2, const float* __restrict__ W1,
                      const float* __restrict__ W2, unsigned short* __restrict__ inputb,
                      unsigned short* __restrict__ w1b, unsigned short* __restrict__ w2b,
                      int* __restrict__ gcur, int n4, int nCvt, int nbuk) {
    int b = blockIdx.x;
    if (b < nCvt) {
        int i = b * 256 + threadIdx.x;
        if (i < n4) {
            int row = i >> 5, q = i & 31;
            float2 a = in2[(long)row * 64 + q];        // dims 2q, 2q+1
            float2 c = in2[(long)row * 64 + 32 + q];   // dims 64+2q, 65+2q
            *(ushort4*)(inputb + (long)row * DIM + q * 4) =
                make_ushort4(f2bf(a.x), f2bf(c.x), f2bf(a.y), f2bf(c.y));
        }
    } else if (b < nCvt + 192) {
        int idx = (b - nCvt) * 256 + threadIdx.x;   // 49152 = 16384 + 32768
        if (idx < 16384)      w1b[idx] = f2bf(W1[idx]);
        else                  w2b[idx - 16384] = f2bf(W2[idx - 16384]);
    } else {
        int i = (b - nCvt - 192) * 256 + threadIdx.x;
        if (i < nbuk) gcur[i] = 0;
    }
}

// ---- pass 1: bucket scatter. Per block: LDS int hist -> chunk reserve -> compact writes ----
// edata[b*BCAP + pos] = ( (row&63)<<17 | col , val )    (col < 2^17)
__global__ __launch_bounds__(256) void k_bucket(const int* __restrict__ er,
                                                const int* __restrict__ ec,
                                                const float* __restrict__ ev,
                                                int* __restrict__ gcur,
                                                int2* __restrict__ edata, int E, int nbuk) {
    __shared__ int lhist[1600];
    __shared__ int lpos[1600];
    for (int b = threadIdx.x; b < nbuk; b += 256) lhist[b] = 0;
    __syncthreads();
    int e0 = blockIdx.x * BK_EDGES;
    for (int j = 0; j < BK_EDGES; j += 256) {
        int e = e0 + j + threadIdx.x;
        if (e < E) atomicAdd(&lhist[er[e] >> 6], 1);        // int LDS atomic: native
    }
    __syncthreads();
    for (int b = threadIdx.x; b < nbuk; b += 256) {
        int c = lhist[b];
        int g = (c > 0) ? atomicAdd(&gcur[b], c) : 0;
        lpos[b] = b * BCAP + g;         // running write cursor for this block's chunk
    }
    __syncthreads();
    for (int j = 0; j < BK_EDGES; j += 256) {
        int e = e0 + j + threadIdx.x;
        if (e < E) {
            int r = er[e], b = r >> 6;
            int p = atomicAdd(&lpos[b], 1);
            if (p < (b + 1) * BCAP)     // capacity guard (statistically never)
                edata[p] = make_int2(((r & 63) << 17) | ec[e], __float_as_int(ev[e]));
        }
    }
}

// ---- gather: one block per bucket, LDS f32 accumulator, ds_add fire-and-forget ----
// No CSR sort needed: edges land in any order, ds_add_f32 is the combiner.
// Lane l owns dims (l, l+64) of every row (split-pair x layout) -> ds_add addresses
// are r*128+l and r*128+64+l: stride-1 across lanes, 2-way bank alias = conflict-free.
__global__ __launch_bounds__(512) void k_gather(const unsigned short* __restrict__ xb,
                                                const int2* __restrict__ edata,
                                                const int* __restrict__ gcur,
                                                unsigned short* __restrict__ aggb, int N) {
    __shared__ float acc[BROWS * DIM];          // 32 KB
    int tid = threadIdx.x, w = tid >> 6, lane = tid & 63;
    int b = blockIdx.x;
    int cnt = gcur[b]; if (cnt > BCAP) cnt = BCAP;
    const int2* ed = edata + (long)b * BCAP;
    for (int i = tid; i < BROWS * DIM / 4; i += 512)
        ((f32x4*)acc)[i] = (f32x4){0.f, 0.f, 0.f, 0.f};
    __syncthreads();

    const unsigned* xw = (const unsigned*)xb;   // word c*64+l packs dims (l, l+64) of row c
    for (int p0 = w * 64; p0 < cnt; p0 += 512) {
        int nc = cnt - p0; if (nc > 64) nc = 64;
        int2 e = (lane < nc) ? ed[p0 + lane] : make_int2(0, 0);
        int j = 0;
        for (; j + 4 <= nc; j += 4) {           // 4 independent gather chains in flight
            int x0 = __shfl(e.x, j);
            int x1 = __shfl(e.x, j + 1);
            int x2 = __shfl(e.x, j + 2);
            int x3 = __shfl(e.x, j + 3);
            float v0 = __int_as_float(__shfl(e.y, j));
            float v1 = __int_as_float(__shfl(e.y, j + 1));
            float v2 = __int_as_float(__shfl(e.y, j + 2));
            float v3 = __int_as_float(__shfl(e.y, j + 3));
            int r0 = x0 >> 17, c0 = x0 & 0x1FFFF;
            int r1 = x1 >> 17, c1 = x1 & 0x1FFFF;
            int r2 = x2 >> 17, c2 = x2 & 0x1FFFF;
            int r3 = x3 >> 17, c3 = x3 & 0x1FFFF;
            unsigned u0 = xw[(long)c0 * 64 + lane];
            unsigned u1 = xw[(long)c1 * 64 + lane];
            unsigned u2 = xw[(long)c2 * 64 + lane];
            unsigned u3 = xw[(long)c3 * 64 + lane];
            atomicAdd(&acc[r0 * DIM + lane],      v0 * __uint_as_float(u0 << 16));
            atomicAdd(&acc[r0 * DIM + 64 + lane], v0 * __uint_as_float(u0 & 0xffff0000u));
            atomicAdd(&acc[r1 * DIM + lane],      v1 * __uint_as_float(u1 << 16));
            atomicAdd(&acc[r1 * DIM + 64 + lane], v1 * __uint_as_float(u1 & 0xffff0000u));
            atomicAdd(&acc[r2 * DIM + lane],      v2 * __uint_as_float(u2 << 16));
            atomicAdd(&acc[r2 * DIM + 64 + lane], v2 * __uint_as_float(u2 & 0xffff0000u));
            atomicAdd(&acc[r3 * DIM + lane],      v3 * __uint_as_float(u3 << 16));
            atomicAdd(&acc[r3 * DIM + 64 + lane], v3 * __uint_as_float(u3 & 0xffff0000u));
        }
        for (; j < nc; ++j) {
            int x = __shfl(e.x, j);
            float v = __int_as_float(__shfl(e.y, j));
            int r = x >> 17, c = x & 0x1FFFF;
            unsigned u = xw[(long)c * 64 + lane];
            atomicAdd(&acc[r * DIM + lane],      v * __uint_as_float(u << 16));
            atomicAdd(&acc[r * DIM + 64 + lane], v * __uint_as_float(u & 0xffff0000u));
        }
    }
    __syncthreads();

    int row0 = b * BROWS;                       // writeback: standard row-major aggb
    for (int i = tid; i < BROWS * (DIM / 2); i += 512) {
        int r = i >> 6, dp = i & 63;
        int row = row0 + r;
        if (row < N)
            *(ushort2*)(aggb + (long)row * DIM + dp * 2) =
                make_ushort2(f2bf(acc[r * DIM + dp * 2]), f2bf(acc[r * DIM + dp * 2 + 1]));
    }
}

// ---- fused MFMA: out = leaky_relu([x+agg@W1^T, x*(agg@W1^T)] @ W2^T) ----
// 64 rows/block, 4 waves; each wave owns 2 output-column tiles for all 64 rows.
// B fragments hoisted into registers once; weight L2 traffic = 1 copy per block.
// NOTE: inputb is in split-pair layout -> x dim d lives at word offset (d&63)*2 | d>>6.
__global__ __launch_bounds__(256, 4) void k_fused(const unsigned short* __restrict__ aggb,
                                                  const unsigned short* __restrict__ inputb,
                                                  const unsigned short* __restrict__ w1b,
                                                  const unsigned short* __restrict__ w2b,
                                                  float* __restrict__ out, int N) {
    __shared__ __align__(16) unsigned short sh[2 * 64 * 136];   // h0 | h1, rows padded to 136
    int w = threadIdx.x >> 6, lane = threadIdx.x & 63;
    int quad = lane >> 4, lq = lane & 15;
    int blk0 = blockIdx.x * 64;
    unsigned short* sh0 = sh;
    unsigned short* sh1 = sh + 64 * 136;

    // ---- hoisted gemm1 B fragments: nt = 2w, 2w+1 (8 frags = 32 VGPR, issued as a batch)
    short8 b1[2][4];
#pragma unroll
    for (int ntl = 0; ntl < 2; ++ntl)
#pragma unroll
        for (int kb = 0; kb < 4; ++kb)
            b1[ntl][kb] = *(const short8*)(w1b + ((w * 2 + ntl) * 16 + lq) * DIM +
                                           kb * 32 + quad * 8);

    // ---- gemm1 + h write, fused per m-tile to bound VGPR pressure ----
#pragma unroll
    for (int mt = 0; mt < 4; ++mt) {
        short8 afr[4];
        {
            int row = blk0 + mt * 16 + lq; if (row >= N) row = N - 1;
#pragma unroll
            for (int kb = 0; kb < 4; ++kb)
                afr[kb] = *(const short8*)(aggb + (long)row * DIM + kb * 32 + quad * 8);
        }
#pragma unroll
        for (int ntl = 0; ntl < 2; ++ntl) {
            f32x4 c = {0.f, 0.f, 0.f, 0.f};
#pragma unroll
            for (int kb = 0; kb < 4; ++kb)
                c = __builtin_amdgcn_mfma_f32_16x16x32_bf16(afr[kb], b1[ntl][kb], c, 0, 0, 0);
            int nt = w * 2 + ntl;
            int d = nt * 16 + lq;
            int dpos = ((d & 63) << 1) | (d >> 6);      // split-pair remap
#pragma unroll
            for (int rg = 0; rg < 4; ++rg) {
                int r = blk0 + mt * 16 + quad * 4 + rg;
                int rr = (r < N) ? r : (N - 1);
                float x = bf2f(inputb[(long)rr * DIM + dpos]);
                float nb = c[rg];
                int off = (mt * 16 + quad * 4 + rg) * 136 + nt * 16 + lq;
                sh0[off] = f2bf(x + nb);
                sh1[off] = f2bf(x * nb);
            }
        }
    }

    // ---- hoisted gemm2 B fragments (16 frags = 64 VGPR), issued BEFORE the barrier ----
    short8 b2[2][8];
#pragma unroll
    for (int ntl = 0; ntl < 2; ++ntl)
#pragma unroll
        for (int kb = 0; kb < 8; ++kb)
            b2[ntl][kb] = *(const short8*)(w2b + ((w * 2 + ntl) * 16 + lq) * 256 +
                                           kb * 32 + quad * 8);
    __syncthreads();

    // ---- gemm2 (K=256 over two h halves) + leaky_relu epilogue, direct store ----
#pragma unroll
    for (int mt = 0; mt < 4; ++mt) {
        int arow = (mt * 16 + lq) * 136;
        short8 a0[4], a1[4];
#pragma unroll
        for (int kb = 0; kb < 4; ++kb) {
            a0[kb] = *(const short8*)(sh0 + arow + kb * 32 + quad * 8);
            a1[kb] = *(const short8*)(sh1 + arow + kb * 32 + quad * 8);
        }
#pragma unroll
        for (int ntl = 0; ntl < 2; ++ntl) {
            f32x4 c = {0.f, 0.f, 0.f, 0.f};
#pragma unroll
            for (int kb = 0; kb < 4; ++kb)
                c = __builtin_amdgcn_mfma_f32_16x16x32_bf16(a0[kb], b2[ntl][kb], c, 0, 0, 0);
#pragma unroll
            for (int kb = 0; kb < 4; ++kb)
                c = __builtin_amdgcn_mfma_f32_16x16x32_bf16(a1[kb], b2[ntl][kb + 4], c, 0, 0, 0);
            int nt = w * 2 + ntl;
#pragma unroll
            for (int rg = 0; rg < 4; ++rg) {
                int r = blk0 + mt * 16 + quad * 4 + rg;
                if (r < N) {
                    float v = c[rg];
                    v = (v > 0.f) ? v : 0.01f * v;
                    out[(long)r * DIM + nt * 16 + lq] = v;
                }
            }
        }
    }
}

extern "C" void kernel_launch(void* const* d_in, const int* in_sizes, int n_in,
                              void* d_out, int out_size, void* d_ws, size_t ws_size,
                              hipStream_t stream) {
    const float* input = (const float*)d_in[0];
    const int*   er    = (const int*)d_in[1];
    const int*   ec    = (const int*)d_in[2];
    const float* ev    = (const float*)d_in[3];
    const float* W1    = (const float*)d_in[4];
    const float* W2    = (const float*)d_in[5];
    int N = in_sizes[0] / DIM;      // 100000
    int E = in_sizes[1];            // 1600000
    float* out = (float*)d_out;
    int nbuk = (N + BROWS - 1) / BROWS;     // 1563

    // ---- workspace layout (~70 MB, all chunks 16B-aligned) ----
    int* ws = (int*)d_ws;
    int* gcur = ws;                                                      // nbuk ints (pad 2048)
    int2* edata = (int2*)(ws + 2048);                                    // nbuk*BCAP int2
    unsigned short* w1b = (unsigned short*)(edata + (long)nbuk * BCAP);  // 16384 bf16
    unsigned short* w2b = w1b + 16384;                                   // 32768 bf16
    unsigned short* inputb = w2b + 32768;                                // N*DIM bf16
    unsigned short* aggb = inputb + (long)N * DIM;                       // N*DIM bf16

    int n4 = N * 32;
    int nCvt = (n4 + 255) / 256;
    int nZero = (nbuk + 255) / 256;
    k_pre<<<nCvt + 192 + nZero, 256, 0, stream>>>(
        (const float2*)input, W1, W2, inputb, w1b, w2b, gcur, n4, nCvt, nbuk);

    k_bucket<<<(E + BK_EDGES - 1) / BK_EDGES, 256, 0, stream>>>(
        er, ec, ev, gcur, edata, E, nbuk);

    k_gather<<<nbuk, 512, 0, stream>>>(inputb, edata, gcur, aggb, N);

    k_fused<<<(N + 63) / 64, 256, 0, stream>>>(aggb, inputb, w1b, w2b, out, N);
}

// Round 4
// 280.277 us; speedup vs baseline: 5.0662x; 5.0662x over previous
//
#include <hip/hip_runtime.h>

#define DIM 128
#define BROWS 128               // rows per bucket (row >> 7)
#define BCAP 3072               // edata capacity per bucket (mean 2046, +22 sigma)
#define BK_EDGES 2048           // edges per k_bucket block (782 blocks -> full CU spread)

typedef __attribute__((ext_vector_type(8))) short short8;   // 8 x bf16 (4 VGPR)
typedef __attribute__((ext_vector_type(4))) float f32x4;    // 4 x f32  (4 VGPR)

__device__ __forceinline__ unsigned short f2bf(float f) {   // RNE fp32->bf16
    unsigned u = __float_as_uint(f);
    u += 0x7fffu + ((u >> 16) & 1u);
    return (unsigned short)(u >> 16);
}
__device__ __forceinline__ float bf2f(unsigned short b) {
    return __uint_as_float(((unsigned)b) << 16);
}

// ---- merged pre-pass: input fp32->bf16, W1/W2 fp32->bf16, zero gcur (one launch) ----
__global__ void k_pre(const float4* __restrict__ in, const float* __restrict__ W1,
                      const float* __restrict__ W2, unsigned short* __restrict__ inputb,
                      unsigned short* __restrict__ w1b, unsigned short* __restrict__ w2b,
                      int* __restrict__ gcur, int n4, int nCvt, int nbuk) {
    int b = blockIdx.x;
    if (b < nCvt) {
        int i = b * 256 + threadIdx.x;
        if (i < n4) {
            float4 v = in[i];
            *(ushort4*)(inputb + (long)i * 4) =
                make_ushort4(f2bf(v.x), f2bf(v.y), f2bf(v.z), f2bf(v.w));
        }
    } else if (b < nCvt + 192) {
        int idx = (b - nCvt) * 256 + threadIdx.x;   // 49152 = 16384 + 32768
        if (idx < 16384)      w1b[idx] = f2bf(W1[idx]);
        else                  w2b[idx - 16384] = f2bf(W2[idx - 16384]);
    } else {
        int i = (b - nCvt - 192) * 256 + threadIdx.x;
        if (i < nbuk) gcur[i] = 0;
    }
}

// ---- pass 1: bucket scatter. Per block: LDS int hist -> chunk reserve -> compact writes ----
// edata[b*BCAP + pos] = ( (row&127)<<17 | col , val )    (col < 2^17)
__global__ __launch_bounds__(256) void k_bucket(const int* __restrict__ er,
                                                const int* __restrict__ ec,
                                                const float* __restrict__ ev,
                                                int* __restrict__ gcur,
                                                int2* __restrict__ edata, int E, int nbuk) {
    __shared__ int lhist[800];
    __shared__ int lpos[800];
    for (int b = threadIdx.x; b < nbuk; b += 256) lhist[b] = 0;
    __syncthreads();
    int e0 = blockIdx.x * BK_EDGES;
    for (int j = 0; j < BK_EDGES; j += 256) {
        int e = e0 + j + threadIdx.x;
        if (e < E) atomicAdd(&lhist[er[e] >> 7], 1);        // int LDS atomic: native
    }
    __syncthreads();
    for (int b = threadIdx.x; b < nbuk; b += 256) {
        int c = lhist[b];
        int g = (c > 0) ? atomicAdd(&gcur[b], c) : 0;
        lpos[b] = b * BCAP + g;         // running write cursor for this block's chunk
    }
    __syncthreads();
    for (int j = 0; j < BK_EDGES; j += 256) {
        int e = e0 + j + threadIdx.x;
        if (e < E) {
            int r = er[e], b = r >> 7;
            int p = atomicAdd(&lpos[b], 1);
            if (p < (b + 1) * BCAP)     // capacity guard (statistically never)
                edata[p] = make_int2(((r & 127) << 17) | ec[e], __float_as_int(ev[e]));
        }
    }
}

// ---- pass 2: per-bucket CSR sort, fully in LDS, written back in place ----
__global__ __launch_bounds__(256) void k_csr(int2* __restrict__ edata,
                                             const int* __restrict__ gcur,
                                             int* __restrict__ rs, int* __restrict__ re) {
    __shared__ int2 sed[BCAP];          // 24 KB
    __shared__ int hist[BROWS];
    __shared__ int scan[BROWS];
    __shared__ int lcur[BROWS];
    int b = blockIdx.x, tid = threadIdx.x;
    int cnt = gcur[b]; if (cnt > BCAP) cnt = BCAP;
    int2* ed = edata + (long)b * BCAP;
    if (tid < BROWS) hist[tid] = 0;
    for (int i = tid; i < cnt; i += 256) sed[i] = ed[i];
    __syncthreads();
    for (int i = tid; i < cnt; i += 256) atomicAdd(&hist[sed[i].x >> 17], 1);
    __syncthreads();
    if (tid < BROWS) scan[tid] = hist[tid];
    __syncthreads();
    for (int off = 1; off < BROWS; off <<= 1) {             // Hillis-Steele inclusive
        int v = (tid < BROWS && tid >= off) ? scan[tid - off] : 0;
        __syncthreads();
        if (tid < BROWS) scan[tid] += v;
        __syncthreads();
    }
    if (tid < BROWS) {
        int excl = scan[tid] - hist[tid];
        lcur[tid] = excl;
        int row = b * BROWS + tid;                          // rs/re sized nbuk*BROWS
        rs[row] = b * BCAP + excl;
        re[row] = b * BCAP + excl + hist[tid];
    }
    __syncthreads();
    for (int i = tid; i < cnt; i += 256) {
        int2 v = sed[i];
        int p = atomicAdd(&lcur[v.x >> 17], 1);
        ed[p] = make_int2(v.x & 0x1FFFF, v.y);              // strip row bits: (col,val)
    }
}

// ---- gather: one wave per row, FAT LOADS: 8 lanes/edge, dwordx4 (16B) per lane ----
// Per 8-edge chunk: 1 edata load + 2 x-loads (was 8 serial 256B wave-loads).
// Register accumulation (NO atomics -> compiler pipelines loads across chunks).
// Row-end: 3-round shfl_xor butterfly over edge-slots; lanes 0-7 store the row.
__global__ __launch_bounds__(256) void k_gather(const unsigned short* __restrict__ xb,
                                                const int2* __restrict__ edata,
                                                const int* __restrict__ rs,
                                                const int* __restrict__ re,
                                                unsigned short* __restrict__ aggb, int N) {
    int wave = threadIdx.x >> 6, lane = threadIdx.x & 63;
    int row = blockIdx.x * 4 + wave;
    if (row >= N) return;
    int beg = rs[row], end = re[row];
    int g = lane >> 3, s = lane & 7;        // edge-slot (0..7), dim-slot (0..7)
    float pa[8], pb[8];                     // dims s*8+j  and  64+s*8+j
#pragma unroll
    for (int k = 0; k < 8; ++k) { pa[k] = 0.f; pb[k] = 0.f; }
    const int4* x4 = (const int4*)xb;       // 16 x int4 per 256B x-row
    for (int p = beg; p < end; p += 8) {
        int idx = p + g;
        int2 e = (idx < end) ? edata[idx] : make_int2(0, 0);    // (col, val); val=0 pad
        float v = __int_as_float(e.y);
        long base = (long)e.x * 16;
        int4 ua = x4[base + s];             // dims s*8 .. s*8+7
        int4 ub = x4[base + 8 + s];         // dims 64+s*8 .. 64+s*8+7
        const unsigned* wa = (const unsigned*)&ua;
        const unsigned* wb = (const unsigned*)&ub;
#pragma unroll
        for (int k = 0; k < 4; ++k) {
            pa[2 * k]     += v * __uint_as_float(wa[k] << 16);
            pa[2 * k + 1] += v * __uint_as_float(wa[k] & 0xffff0000u);
            pb[2 * k]     += v * __uint_as_float(wb[k] << 16);
            pb[2 * k + 1] += v * __uint_as_float(wb[k] & 0xffff0000u);
        }
    }
    // butterfly reduce across the 8 edge-slots (xor 8,16,32 preserves dim-slot s)
#pragma unroll
    for (int m = 8; m <= 32; m <<= 1) {
#pragma unroll
        for (int k = 0; k < 8; ++k) {
            pa[k] += __shfl_xor(pa[k], m);
            pb[k] += __shfl_xor(pb[k], m);
        }
    }
    if (g == 0) {                           // lane s stores dims s*8.. and 64+s*8..
        short8 oa, ob;
#pragma unroll
        for (int k = 0; k < 8; ++k) {
            oa[k] = (short)f2bf(pa[k]);
            ob[k] = (short)f2bf(pb[k]);
        }
        *(short8*)(aggb + (long)row * DIM + s * 8)      = oa;
        *(short8*)(aggb + (long)row * DIM + 64 + s * 8) = ob;
    }
}

// ---- fused MFMA: out = leaky_relu([x+agg@W1^T, x*(agg@W1^T)] @ W2^T) ----
// 64 rows/block, 4 waves; each wave owns 2 output-column tiles for all 64 rows.
// B fragments hoisted into registers once; weight L2 traffic = 1 copy per block.
__global__ __launch_bounds__(256, 4) void k_fused(const unsigned short* __restrict__ aggb,
                                                  const unsigned short* __restrict__ inputb,
                                                  const unsigned short* __restrict__ w1b,
                                                  const unsigned short* __restrict__ w2b,
                                                  float* __restrict__ out, int N) {
    __shared__ __align__(16) unsigned short sh[2 * 64 * 136];   // h0 | h1, rows padded to 136
    int w = threadIdx.x >> 6, lane = threadIdx.x & 63;
    int quad = lane >> 4, lq = lane & 15;
    int blk0 = blockIdx.x * 64;
    unsigned short* sh0 = sh;
    unsigned short* sh1 = sh + 64 * 136;

    // ---- hoisted gemm1 B fragments: nt = 2w, 2w+1 (8 frags = 32 VGPR, issued as a batch)
    short8 b1[2][4];
#pragma unroll
    for (int ntl = 0; ntl < 2; ++ntl)
#pragma unroll
        for (int kb = 0; kb < 4; ++kb)
            b1[ntl][kb] = *(const short8*)(w1b + ((w * 2 + ntl) * 16 + lq) * DIM +
                                           kb * 32 + quad * 8);

    // ---- gemm1 + h write, fused per m-tile to bound VGPR pressure ----
#pragma unroll
    for (int mt = 0; mt < 4; ++mt) {
        short8 afr[4];
        {
            int row = blk0 + mt * 16 + lq; if (row >= N) row = N - 1;
#pragma unroll
            for (int kb = 0; kb < 4; ++kb)
                afr[kb] = *(const short8*)(aggb + (long)row * DIM + kb * 32 + quad * 8);
        }
#pragma unroll
        for (int ntl = 0; ntl < 2; ++ntl) {
            f32x4 c = {0.f, 0.f, 0.f, 0.f};
#pragma unroll
            for (int kb = 0; kb < 4; ++kb)
                c = __builtin_amdgcn_mfma_f32_16x16x32_bf16(afr[kb], b1[ntl][kb], c, 0, 0, 0);
            int nt = w * 2 + ntl;
#pragma unroll
            for (int rg = 0; rg < 4; ++rg) {
                int r = blk0 + mt * 16 + quad * 4 + rg;
                int rr = (r < N) ? r : (N - 1);
                float x = bf2f(inputb[(long)rr * DIM + nt * 16 + lq]);
                float nb = c[rg];
                int off = (mt * 16 + quad * 4 + rg) * 136 + nt * 16 + lq;
                sh0[off] = f2bf(x + nb);
                sh1[off] = f2bf(x * nb);
            }
        }
    }

    // ---- hoisted gemm2 B fragments (16 frags = 64 VGPR), issued BEFORE the barrier ----
    short8 b2[2][8];
#pragma unroll
    for (int ntl = 0; ntl < 2; ++ntl)
#pragma unroll
        for (int kb = 0; kb < 8; ++kb)
            b2[ntl][kb] = *(const short8*)(w2b + ((w * 2 + ntl) * 16 + lq) * 256 +
                                           kb * 32 + quad * 8);
    __syncthreads();

    // ---- gemm2 (K=256 over two h halves) + leaky_relu epilogue, direct store ----
#pragma unroll
    for (int mt = 0; mt < 4; ++mt) {
        int arow = (mt * 16 + lq) * 136;
        short8 a0[4], a1[4];
#pragma unroll
        for (int kb = 0; kb < 4; ++kb) {
            a0[kb] = *(const short8*)(sh0 + arow + kb * 32 + quad * 8);
            a1[kb] = *(const short8*)(sh1 + arow + kb * 32 + quad * 8);
        }
#pragma unroll
        for (int ntl = 0; ntl < 2; ++ntl) {
            f32x4 c = {0.f, 0.f, 0.f, 0.f};
#pragma unroll
            for (int kb = 0; kb < 4; ++kb)
                c = __builtin_amdgcn_mfma_f32_16x16x32_bf16(a0[kb], b2[ntl][kb], c, 0, 0, 0);
#pragma unroll
            for (int kb = 0; kb < 4; ++kb)
                c = __builtin_amdgcn_mfma_f32_16x16x32_bf16(a1[kb], b2[ntl][kb + 4], c, 0, 0, 0);
            int nt = w * 2 + ntl;
#pragma unroll
            for (int rg = 0; rg < 4; ++rg) {
                int r = blk0 + mt * 16 + quad * 4 + rg;
                if (r < N) {
                    float v = c[rg];
                    v = (v > 0.f) ? v : 0.01f * v;
                    out[(long)r * DIM + nt * 16 + lq] = v;
                }
            }
        }
    }
}

extern "C" void kernel_launch(void* const* d_in, const int* in_sizes, int n_in,
                              void* d_out, int out_size, void* d_ws, size_t ws_size,
                              hipStream_t stream) {
    const float* input = (const float*)d_in[0];
    const int*   er    = (const int*)d_in[1];
    const int*   ec    = (const int*)d_in[2];
    const float* ev    = (const float*)d_in[3];
    const float* W1    = (const float*)d_in[4];
    const float* W2    = (const float*)d_in[5];
    int N = in_sizes[0] / DIM;      // 100000
    int E = in_sizes[1];            // 1600000
    float* out = (float*)d_out;
    int nbuk = (N + BROWS - 1) / BROWS;     // 782

    // ---- workspace layout (~71 MB, all chunks 16B-aligned) ----
    int* ws = (int*)d_ws;
    int* gcur = ws;                                                      // nbuk ints (pad 1024)
    int2* edata = (int2*)(ws + 1024);                                    // nbuk*BCAP int2
    int* rs = (int*)(edata + (long)nbuk * BCAP);                         // nbuk*BROWS ints
    int* re = rs + (long)nbuk * BROWS;                                   // nbuk*BROWS ints
    unsigned short* w1b = (unsigned short*)(re + (long)nbuk * BROWS);    // 16384 bf16
    unsigned short* w2b = w1b + 16384;                                   // 32768 bf16
    unsigned short* inputb = w2b + 32768;                                // N*DIM bf16
    unsigned short* aggb = inputb + (long)N * DIM;                       // N*DIM bf16

    int n4 = N * (DIM / 4);
    int nCvt = (n4 + 255) / 256;
    int nZero = (nbuk + 255) / 256;
    k_pre<<<nCvt + 192 + nZero, 256, 0, stream>>>(
        (const float4*)input, W1, W2, inputb, w1b, w2b, gcur, n4, nCvt, nbuk);

    k_bucket<<<(E + BK_EDGES - 1) / BK_EDGES, 256, 0, stream>>>(
        er, ec, ev, gcur, edata, E, nbuk);

    k_csr<<<nbuk, 256, 0, stream>>>(edata, gcur, rs, re);

    k_gather<<<(N + 3) / 4, 256, 0, stream>>>(inputb, edata, rs, re, aggb, N);

    k_fused<<<(N + 63) / 64, 256, 0, stream>>>(aggb, inputb, w1b, w2b, out, N);
}

// Round 5
// 275.901 us; speedup vs baseline: 5.1466x; 1.0159x over previous
//
#include <hip/hip_runtime.h>

#define DIM 128
#define BROWS 128               // rows per bucket (row >> 7)
#define BCAP 3072               // edata capacity per bucket (mean 2046, +22 sigma)
#define BK_EDGES 2048           // edges per k_bucket block (782 blocks -> full CU spread)

typedef __attribute__((ext_vector_type(8))) short short8;   // 8 x bf16 (4 VGPR)
typedef __attribute__((ext_vector_type(4))) float f32x4;    // 4 x f32  (4 VGPR)

__device__ __forceinline__ unsigned short f2bf(float f) {   // RNE fp32->bf16
    unsigned u = __float_as_uint(f);
    u += 0x7fffu + ((u >> 16) & 1u);
    return (unsigned short)(u >> 16);
}
__device__ __forceinline__ float bf2f(unsigned short b) {
    return __uint_as_float(((unsigned)b) << 16);
}

// ---- merged pre-pass: input fp32->bf16, W1/W2 fp32->bf16, zero gcur (one launch) ----
__global__ void k_pre(const float4* __restrict__ in, const float* __restrict__ W1,
                      const float* __restrict__ W2, unsigned short* __restrict__ inputb,
                      unsigned short* __restrict__ w1b, unsigned short* __restrict__ w2b,
                      int* __restrict__ gcur, int n4, int nCvt, int nbuk) {
    int b = blockIdx.x;
    if (b < nCvt) {
        int i = b * 256 + threadIdx.x;
        if (i < n4) {
            float4 v = in[i];
            *(ushort4*)(inputb + (long)i * 4) =
                make_ushort4(f2bf(v.x), f2bf(v.y), f2bf(v.z), f2bf(v.w));
        }
    } else if (b < nCvt + 192) {
        int idx = (b - nCvt) * 256 + threadIdx.x;   // 49152 = 16384 + 32768
        if (idx < 16384)      w1b[idx] = f2bf(W1[idx]);
        else                  w2b[idx - 16384] = f2bf(W2[idx - 16384]);
    } else {
        int i = (b - nCvt - 192) * 256 + threadIdx.x;
        if (i < nbuk) gcur[i] = 0;
    }
}

// ---- pass 1: bucket scatter. Per block: LDS int hist -> chunk reserve -> compact writes ----
// edata[b*BCAP + pos] = ( (row&127)<<17 | col , val )    (col < 2^17)
__global__ __launch_bounds__(256) void k_bucket(const int* __restrict__ er,
                                                const int* __restrict__ ec,
                                                const float* __restrict__ ev,
                                                int* __restrict__ gcur,
                                                int2* __restrict__ edata, int E, int nbuk) {
    __shared__ int lhist[800];
    __shared__ int lpos[800];
    for (int b = threadIdx.x; b < nbuk; b += 256) lhist[b] = 0;
    __syncthreads();
    int e0 = blockIdx.x * BK_EDGES;
    for (int j = 0; j < BK_EDGES; j += 256) {
        int e = e0 + j + threadIdx.x;
        if (e < E) atomicAdd(&lhist[er[e] >> 7], 1);        // int LDS atomic: native
    }
    __syncthreads();
    for (int b = threadIdx.x; b < nbuk; b += 256) {
        int c = lhist[b];
        int g = (c > 0) ? atomicAdd(&gcur[b], c) : 0;
        lpos[b] = b * BCAP + g;         // running write cursor for this block's chunk
    }
    __syncthreads();
    for (int j = 0; j < BK_EDGES; j += 256) {
        int e = e0 + j + threadIdx.x;
        if (e < E) {
            int r = er[e], b = r >> 7;
            int p = atomicAdd(&lpos[b], 1);
            if (p < (b + 1) * BCAP)     // capacity guard (statistically never)
                edata[p] = make_int2(((r & 127) << 17) | ec[e], __float_as_int(ev[e]));
        }
    }
}

// ---- pass 2: per-bucket CSR sort, fully in LDS, written back in place ----
__global__ __launch_bounds__(256) void k_csr(int2* __restrict__ edata,
                                             const int* __restrict__ gcur,
                                             int* __restrict__ rs, int* __restrict__ re) {
    __shared__ int2 sed[BCAP];          // 24 KB
    __shared__ int hist[BROWS];
    __shared__ int scan[BROWS];
    __shared__ int lcur[BROWS];
    int b = blockIdx.x, tid = threadIdx.x;
    int cnt = gcur[b]; if (cnt > BCAP) cnt = BCAP;
    int2* ed = edata + (long)b * BCAP;
    if (tid < BROWS) hist[tid] = 0;
    for (int i = tid; i < cnt; i += 256) sed[i] = ed[i];
    __syncthreads();
    for (int i = tid; i < cnt; i += 256) atomicAdd(&hist[sed[i].x >> 17], 1);
    __syncthreads();
    if (tid < BROWS) scan[tid] = hist[tid];
    __syncthreads();
    for (int off = 1; off < BROWS; off <<= 1) {             // Hillis-Steele inclusive
        int v = (tid < BROWS && tid >= off) ? scan[tid - off] : 0;
        __syncthreads();
        if (tid < BROWS) scan[tid] += v;
        __syncthreads();
    }
    if (tid < BROWS) {
        int excl = scan[tid] - hist[tid];
        lcur[tid] = excl;
        int row = b * BROWS + tid;                          // rs/re sized nbuk*BROWS
        rs[row] = b * BCAP + excl;
        re[row] = b * BCAP + excl + hist[tid];
    }
    __syncthreads();
    for (int i = tid; i < cnt; i += 256) {
        int2 v = sed[i];
        int p = atomicAdd(&lcur[v.x >> 17], 1);
        ed[p] = make_int2(v.x & 0x1FFFF, v.y);              // strip row bits: (col,val)
    }
}

// ---- gather: 16 lanes per row, 4 rows per wave, NO cross-lane reduction tail ----
// Lane (grp, s) owns dims s*8..s*8+7 of its row and accumulates them across ALL
// edges -> after the loop the lane holds the final value (tail = 8 f2bf + 1 store).
// Edges preloaded 16/group (1 coalesced load), broadcast via intra-group shfl;
// 4-unrolled so 4 independent 16B x-loads stay in flight. Register accumulation.
__global__ __launch_bounds__(256) void k_gather(const unsigned short* __restrict__ xb,
                                                const int2* __restrict__ edata,
                                                const int* __restrict__ rs,
                                                const int* __restrict__ re,
                                                unsigned short* __restrict__ aggb, int N) {
    int tid = threadIdx.x, lane = tid & 63, wave = tid >> 6;
    int grp = lane >> 4, s = lane & 15;     // row-group (0..3), dim-slot (0..15)
    int row = blockIdx.x * 16 + wave * 4 + grp;
    int beg = 0, end = 0;
    if (row < N) { beg = rs[row]; end = re[row]; }
    int deg = end - beg;
    int m = deg;                            // wave-uniform max degree over 4 groups
    m = max(m, __shfl_xor(m, 16));
    m = max(m, __shfl_xor(m, 32));
    float pa[8];
#pragma unroll
    for (int k = 0; k < 8; ++k) pa[k] = 0.f;
    const int4* x4 = (const int4*)xb;       // 16 x int4 per 256B x-row
    int bsrc = lane & 48;                   // group base lane for broadcasts

#define ACC8(U, V)                                                         \
    {                                                                      \
        const unsigned* wp_ = (const unsigned*)&(U);                       \
        pa[0] += (V) * __uint_as_float(wp_[0] << 16);                      \
        pa[1] += (V) * __uint_as_float(wp_[0] & 0xffff0000u);              \
        pa[2] += (V) * __uint_as_float(wp_[1] << 16);                      \
        pa[3] += (V) * __uint_as_float(wp_[1] & 0xffff0000u);              \
        pa[4] += (V) * __uint_as_float(wp_[2] << 16);                      \
        pa[5] += (V) * __uint_as_float(wp_[2] & 0xffff0000u);              \
        pa[6] += (V) * __uint_as_float(wp_[3] << 16);                      \
        pa[7] += (V) * __uint_as_float(wp_[3] & 0xffff0000u);              \
    }

    for (int c0 = 0; c0 < m; c0 += 16) {
        int idx = beg + c0 + s;             // lane s holds edge (c0+s) of its group
        int2 ed = (idx < end) ? edata[idx] : make_int2(0, 0);   // pad: col 0, val 0
        int nc = m - c0; if (nc > 16) nc = 16;
        nc = (nc + 3) & ~3;                 // padded slots are (0,0) -> contribute 0
        for (int j = 0; j < nc; j += 4) {
            int cx0 = __shfl(ed.x, bsrc + j);
            int cx1 = __shfl(ed.x, bsrc + j + 1);
            int cx2 = __shfl(ed.x, bsrc + j + 2);
            int cx3 = __shfl(ed.x, bsrc + j + 3);
            float v0 = __int_as_float(__shfl(ed.y, bsrc + j));
            float v1 = __int_as_float(__shfl(ed.y, bsrc + j + 1));
            float v2 = __int_as_float(__shfl(ed.y, bsrc + j + 2));
            float v3 = __int_as_float(__shfl(ed.y, bsrc + j + 3));
            int4 u0 = x4[(long)cx0 * 16 + s];   // 4 independent 16B loads in flight
            int4 u1 = x4[(long)cx1 * 16 + s];
            int4 u2 = x4[(long)cx2 * 16 + s];
            int4 u3 = x4[(long)cx3 * 16 + s];
            ACC8(u0, v0);
            ACC8(u1, v1);
            ACC8(u2, v2);
            ACC8(u3, v3);
        }
    }
#undef ACC8

    if (row < N) {                          // lane stores its 8 final dims (16B)
        short8 o;
#pragma unroll
        for (int k = 0; k < 8; ++k) o[k] = (short)f2bf(pa[k]);
        *(short8*)(aggb + (long)row * DIM + s * 8) = o;
    }
}

// ---- fused MFMA: out = leaky_relu([x+agg@W1^T, x*(agg@W1^T)] @ W2^T) ----
// 64 rows/block, 4 waves; each wave owns 2 output-column tiles for all 64 rows.
// B fragments hoisted into registers once; weight L2 traffic = 1 copy per block.
__global__ __launch_bounds__(256, 4) void k_fused(const unsigned short* __restrict__ aggb,
                                                  const unsigned short* __restrict__ inputb,
                                                  const unsigned short* __restrict__ w1b,
                                                  const unsigned short* __restrict__ w2b,
                                                  float* __restrict__ out, int N) {
    __shared__ __align__(16) unsigned short sh[2 * 64 * 136];   // h0 | h1, rows padded to 136
    int w = threadIdx.x >> 6, lane = threadIdx.x & 63;
    int quad = lane >> 4, lq = lane & 15;
    int blk0 = blockIdx.x * 64;
    unsigned short* sh0 = sh;
    unsigned short* sh1 = sh + 64 * 136;

    // ---- hoisted gemm1 B fragments: nt = 2w, 2w+1 (8 frags = 32 VGPR, issued as a batch)
    short8 b1[2][4];
#pragma unroll
    for (int ntl = 0; ntl < 2; ++ntl)
#pragma unroll
        for (int kb = 0; kb < 4; ++kb)
            b1[ntl][kb] = *(const short8*)(w1b + ((w * 2 + ntl) * 16 + lq) * DIM +
                                           kb * 32 + quad * 8);

    // ---- gemm1 + h write, fused per m-tile to bound VGPR pressure ----
#pragma unroll
    for (int mt = 0; mt < 4; ++mt) {
        short8 afr[4];
        {
            int row = blk0 + mt * 16 + lq; if (row >= N) row = N - 1;
#pragma unroll
            for (int kb = 0; kb < 4; ++kb)
                afr[kb] = *(const short8*)(aggb + (long)row * DIM + kb * 32 + quad * 8);
        }
#pragma unroll
        for (int ntl = 0; ntl < 2; ++ntl) {
            f32x4 c = {0.f, 0.f, 0.f, 0.f};
#pragma unroll
            for (int kb = 0; kb < 4; ++kb)
                c = __builtin_amdgcn_mfma_f32_16x16x32_bf16(afr[kb], b1[ntl][kb], c, 0, 0, 0);
            int nt = w * 2 + ntl;
#pragma unroll
            for (int rg = 0; rg < 4; ++rg) {
                int r = blk0 + mt * 16 + quad * 4 + rg;
                int rr = (r < N) ? r : (N - 1);
                float x = bf2f(inputb[(long)rr * DIM + nt * 16 + lq]);
                float nb = c[rg];
                int off = (mt * 16 + quad * 4 + rg) * 136 + nt * 16 + lq;
                sh0[off] = f2bf(x + nb);
                sh1[off] = f2bf(x * nb);
            }
        }
    }

    // ---- hoisted gemm2 B fragments (16 frags = 64 VGPR), issued BEFORE the barrier ----
    short8 b2[2][8];
#pragma unroll
    for (int ntl = 0; ntl < 2; ++ntl)
#pragma unroll
        for (int kb = 0; kb < 8; ++kb)
            b2[ntl][kb] = *(const short8*)(w2b + ((w * 2 + ntl) * 16 + lq) * 256 +
                                           kb * 32 + quad * 8);
    __syncthreads();

    // ---- gemm2 (K=256 over two h halves) + leaky_relu epilogue, direct store ----
#pragma unroll
    for (int mt = 0; mt < 4; ++mt) {
        int arow = (mt * 16 + lq) * 136;
        short8 a0[4], a1[4];
#pragma unroll
        for (int kb = 0; kb < 4; ++kb) {
            a0[kb] = *(const short8*)(sh0 + arow + kb * 32 + quad * 8);
            a1[kb] = *(const short8*)(sh1 + arow + kb * 32 + quad * 8);
        }
#pragma unroll
        for (int ntl = 0; ntl < 2; ++ntl) {
            f32x4 c = {0.f, 0.f, 0.f, 0.f};
#pragma unroll
            for (int kb = 0; kb < 4; ++kb)
                c = __builtin_amdgcn_mfma_f32_16x16x32_bf16(a0[kb], b2[ntl][kb], c, 0, 0, 0);
#pragma unroll
            for (int kb = 0; kb < 4; ++kb)
                c = __builtin_amdgcn_mfma_f32_16x16x32_bf16(a1[kb], b2[ntl][kb + 4], c, 0, 0, 0);
            int nt = w * 2 + ntl;
#pragma unroll
            for (int rg = 0; rg < 4; ++rg) {
                int r = blk0 + mt * 16 + quad * 4 + rg;
                if (r < N) {
                    float v = c[rg];
                    v = (v > 0.f) ? v : 0.01f * v;
                    out[(long)r * DIM + nt * 16 + lq] = v;
                }
            }
        }
    }
}

extern "C" void kernel_launch(void* const* d_in, const int* in_sizes, int n_in,
                              void* d_out, int out_size, void* d_ws, size_t ws_size,
                              hipStream_t stream) {
    const float* input = (const float*)d_in[0];
    const int*   er    = (const int*)d_in[1];
    const int*   ec    = (const int*)d_in[2];
    const float* ev    = (const float*)d_in[3];
    const float* W1    = (const float*)d_in[4];
    const float* W2    = (const float*)d_in[5];
    int N = in_sizes[0] / DIM;      // 100000
    int E = in_sizes[1];            // 1600000
    float* out = (float*)d_out;
    int nbuk = (N + BROWS - 1) / BROWS;     // 782

    // ---- workspace layout (~71 MB, all chunks 16B-aligned) ----
    int* ws = (int*)d_ws;
    int* gcur = ws;                                                      // nbuk ints (pad 1024)
    int2* edata = (int2*)(ws + 1024);                                    // nbuk*BCAP int2
    int* rs = (int*)(edata + (long)nbuk * BCAP);                         // nbuk*BROWS ints
    int* re = rs + (long)nbuk * BROWS;                                   // nbuk*BROWS ints
    unsigned short* w1b = (unsigned short*)(re + (long)nbuk * BROWS);    // 16384 bf16
    unsigned short* w2b = w1b + 16384;                                   // 32768 bf16
    unsigned short* inputb = w2b + 32768;                                // N*DIM bf16
    unsigned short* aggb = inputb + (long)N * DIM;                       // N*DIM bf16

    int n4 = N * (DIM / 4);
    int nCvt = (n4 + 255) / 256;
    int nZero = (nbuk + 255) / 256;
    k_pre<<<nCvt + 192 + nZero, 256, 0, stream>>>(
        (const float4*)input, W1, W2, inputb, w1b, w2b, gcur, n4, nCvt, nbuk);

    k_bucket<<<(E + BK_EDGES - 1) / BK_EDGES, 256, 0, stream>>>(
        er, ec, ev, gcur, edata, E, nbuk);

    k_csr<<<nbuk, 256, 0, stream>>>(edata, gcur, rs, re);

    k_gather<<<(N + 15) / 16, 256, 0, stream>>>(inputb, edata, rs, re, aggb, N);

    k_fused<<<(N + 63) / 64, 256, 0, stream>>>(aggb, inputb, w1b, w2b, out, N);
}